// Round 9
// baseline (256.493 us; speedup 1.0000x reference)
//
#include <hip/hip_runtime.h>
#include <hip/hip_bf16.h>

#define DEPTH 2
#define DIM   1024
#define SDIM  256
#define BATCH 256
#define SHOTS 64
#define M_TOT (BATCH*SHOTS)   // 16384

typedef __attribute__((ext_vector_type(8))) short bf16x8;  // 8 bf16 = 4 VGPRs
typedef __attribute__((ext_vector_type(4))) float f32x4;
typedef unsigned short u16;

__device__ __forceinline__ u16 f2bf(float f) {
    union { float f; unsigned u; } v; v.f = f;
    unsigned r = v.u + 0x7fffu + ((v.u >> 16) & 1u);
    return (u16)(r >> 16);
}

__device__ __forceinline__ unsigned pk_bf2(float a, float b) {
    union { __hip_bfloat162 h2; unsigned u; } c;
    c.h2 = __float22bfloat162_rn(make_float2(a, b));   // v_cvt_pk_bf16_f32
    return c.u;
}

__device__ __forceinline__ float bf2f(u16 h) {
    union { unsigned u; float f; } c; c.u = (unsigned)h << 16; return c.f;
}

// fast softplus: 2 HW transcendentals (v_exp_f32 + v_log_f32), no libm.
__device__ __forceinline__ float softplus_f(float x) {
    if (x > 15.f) return x;
    return __logf(1.f + __expf(x));
}

// async global->LDS, 16B per lane (global_load_lds_dwordx4)
__device__ __forceinline__ void gld16(const u16* g, u16* l) {
    __builtin_amdgcn_global_load_lds(
        (const __attribute__((address_space(1))) unsigned int*)g,
        (__attribute__((address_space(3))) unsigned int*)l, 16, 0, 0);
}

// ---------------------------------------------------------------------------
// transpose body: out[destbase+nr][k] (bf16) = in[k][n0+nr] (fp32).
// destbase lets prep permute output rows (P|Q block layout for WcombT).
// ---------------------------------------------------------------------------
__device__ __forceinline__ void transpose_body(
    float T[64][65], const float* __restrict__ A1, const float* __restrict__ A2,
    u16* __restrict__ out, int K, int SPLIT, int k0, int n0, int destbase,
    int layer, int N, int tid)
{
    const bool first = (n0 < SPLIT);
    const int scols = first ? SPLIT : (N - SPLIT);
    const float* S = (first ? A1 : A2) + (size_t)layer * K * scols
                     + (first ? n0 : (n0 - SPLIT));
    out += (size_t)layer * K * N;

    #pragma unroll
    for (int i = 0; i < 4; ++i) {
        const int c = tid + i * 256;
        const int kr = c >> 4, cc = c & 15;
        const float4 v = *(const float4*)(S + (size_t)(k0 + kr) * scols + cc * 4);
        T[kr][cc * 4 + 0] = v.x; T[kr][cc * 4 + 1] = v.y;
        T[kr][cc * 4 + 2] = v.z; T[kr][cc * 4 + 3] = v.w;
    }
    __syncthreads();
    #pragma unroll
    for (int i = 0; i < 4; ++i) {
        const int c = tid + i * 256;
        const int nr = c >> 4, cc = c & 15;
        ushort4 h;
        h.x = f2bf(T[cc * 4 + 0][nr]); h.y = f2bf(T[cc * 4 + 1][nr]);
        h.z = f2bf(T[cc * 4 + 2][nr]); h.w = f2bf(T[cc * 4 + 3][nr]);
        *(ushort4*)&out[(size_t)(destbase + nr) * K + k0 + cc * 4] = h;
    }
}

// ---------------------------------------------------------------------------
// prep: ALL one-time conversions in a single dispatch.
//   blocks [0,256):    WcombT (P|Q block layout: rows [cb*128,+64)=Wd cols
//                      cb*64.., rows [cb*128+64,+64)=Wi cols cb*64..)
//   blocks [256,384):  WoT = transpose+bf16 of Wo
//   blocks [384,640):  Wsb = bf16 copy of Ws (original layout)
//   blocks [640,2688): Xbf = bf16 copy of X0
// ---------------------------------------------------------------------------
__global__ __launch_bounds__(256)
void prep(const float* __restrict__ Wd, const float* __restrict__ Wi,
          const float* __restrict__ Wo, const float* __restrict__ Ws,
          const float* __restrict__ X0,
          u16* __restrict__ WcombT, u16* __restrict__ WoT,
          u16* __restrict__ Wsb, u16* __restrict__ Xbf)
{
    __shared__ float T[64][65];
    const int bid = blockIdx.x;
    const int tid = threadIdx.x;

    if (bid < 256) {
        const int kx = bid & 15, ny = (bid >> 4) & 7, lz = bid >> 7;
        const int n0 = ny * 64;
        // P|Q block layout: Wd col n -> row (n>>6)*128 + (n&63);
        //                   Wi col n -> row (n>>6)*128 + 64 + (n&63)
        const int destbase = (n0 < 256) ? (n0 >> 6) * 128
                                        : ((n0 - 256) >> 6) * 128 + 64;
        transpose_body(T, Wd, Wi, WcombT, 1024, 256, kx * 64, n0, destbase,
                       lz, 512, tid);
    } else if (bid < 384) {
        const int sub = bid - 256;
        const int kx = sub & 3, ny = (sub >> 2) & 15, lz = sub >> 6;
        transpose_body(T, Wo, Wo, WoT, 256, 1024, kx * 64, ny * 64, ny * 64,
                       lz, 1024, tid);
    } else if (bid < 640) {
        const size_t i = ((size_t)(bid - 384) * 256 + tid) * 8;
        const float4 a = *(const float4*)(Ws + i);
        const float4 b = *(const float4*)(Ws + i + 4);
        int4 o;
        o.x = (int)pk_bf2(a.x, a.y); o.y = (int)pk_bf2(a.z, a.w);
        o.z = (int)pk_bf2(b.x, b.y); o.w = (int)pk_bf2(b.z, b.w);
        *(int4*)(Wsb + i) = o;
    } else {
        const size_t total = (size_t)M_TOT * DIM;
        const size_t stride = (size_t)2048 * 256 * 8;
        for (size_t i = ((size_t)(bid - 640) * 256 + tid) * 8; i < total; i += stride) {
            const float4 a = *(const float4*)(X0 + i);
            const float4 b = *(const float4*)(X0 + i + 4);
            int4 o;
            o.x = (int)pk_bf2(a.x, a.y); o.y = (int)pk_bf2(a.z, a.w);
            o.z = (int)pk_bf2(b.x, b.y); o.w = (int)pk_bf2(b.z, b.w);
            *(int4*)(Xbf + i) = o;
        }
    }
}

#define BM 128
#define BN 128
#define BK 64

// BK=64 staging geometry (both GEMMs): 8 gld16 issues per K-step (4 A + 4 B),
// issue i covers rows [i*32 + w*8 + (l>>3)], bf16 col (l&7)*8; LDS dest
// (w*64+l)*8 + i*2048 == linear row-major [128][64]. Same bytes per K-step
// as BK=32 but HALF the barrier/vmcnt-drain count per MFMA.

// ---------------------------------------------------------------------------
// gemm_pq_scan: PQ = Xbf @ WcombT^T with the selective scan FUSED into the
// epilogue. Tile 128x128 = 2 batches x (P|Q for 64 states). Per batch:
// acc -> LDS Ct[64][129] fp32, 4-segment scan (threads = 4 seg x 64 cols,
// lane-consecutive -> conflict-free), hs -> global bf16, state -> fp32.
// Ct/grp UNION the staging LDS (disjoint live ranges, separated by the
// K-loop's trailing barrier) -> 35 KB total.
// ---------------------------------------------------------------------------
__global__ __launch_bounds__(256)
void gemm_pq_scan(const u16* __restrict__ A, const u16* __restrict__ BT,
                  const float* __restrict__ bd, const float* __restrict__ bi,
                  const float* __restrict__ A_log,
                  u16* __restrict__ hsb, float* __restrict__ stateb, int CB)
{
    __shared__ __align__(16) char pool[35072];
    u16* As = (u16*)pool;               // 16 KiB (K-loop only)
    u16* Bs = (u16*)(pool + 16384);     // 16 KiB (K-loop only)
    float (*Ct)[129]  = (float(*)[129])pool;          // 33024 B (epilogue)
    float2 (*grp)[64] = (float2(*)[64])(pool + 33024); // 2048 B (epilogue)

    const int tid = threadIdx.x;
    const int id  = blockIdx.x;
    const int xcd = id & 7, slot = id >> 3;
    const int rb = xcd + 8 * (slot / CB);
    const int cb = slot % CB;
    const int row0 = rb * BM, col0 = cb * BN;
    const int K = 1024;

    const int l  = tid & 63;
    const int w  = tid >> 6;
    const int wm = (w >> 1) * 64, wn = (w & 1) * 64;
    const int lr = l & 15, lq = l >> 4;

    // BK=64 staging: see comment above
    const int srow = w * 8 + (l >> 3);
    const int scol = (l & 7) * 8;
    const u16* Ag = A  + (size_t)(row0 + srow) * K + scol;
    const u16* Bg = BT + (size_t)(col0 + srow) * K + scol;
    u16* Asd = &As[(w * 64 + l) * 8];
    u16* Bsd = &Bs[(w * 64 + l) * 8];

    f32x4 acc[4][4];
    #pragma unroll
    for (int i = 0; i < 4; ++i)
        #pragma unroll
        for (int j = 0; j < 4; ++j)
            acc[i][j] = (f32x4){0.f, 0.f, 0.f, 0.f};

    for (int k0 = 0; k0 < K; k0 += BK) {
        #pragma unroll
        for (int i = 0; i < 4; ++i) {
            gld16(Ag + (size_t)(i * 32) * K + k0, Asd + i * 2048);
            gld16(Bg + (size_t)(i * 32) * K + k0, Bsd + i * 2048);
        }
        __syncthreads();

        #pragma unroll
        for (int ks = 0; ks < 2; ++ks) {
            bf16x8 af[4], bfr[4];
            #pragma unroll
            for (int i = 0; i < 4; ++i)
                af[i] = *(const bf16x8*)&As[(wm + i * 16 + lr) * BK + ks * 32 + lq * 8];
            #pragma unroll
            for (int j = 0; j < 4; ++j)
                bfr[j] = *(const bf16x8*)&Bs[(wn + j * 16 + lr) * BK + ks * 32 + lq * 8];
            #pragma unroll
            for (int i = 0; i < 4; ++i)
                #pragma unroll
                for (int j = 0; j < 4; ++j)
                    acc[i][j] = __builtin_amdgcn_mfma_f32_16x16x32_bf16(
                        af[i], bfr[j], acc[i][j], 0, 0, 0);
        }
        __syncthreads();
    }

    // fused scan epilogue. tile col c<64 = P_{n0+c}, c>=64 = Q_{n0+c-64}
    const int n0  = cb * 64;
    const int seg = tid >> 6;        // == wave id
    const int nl  = tid & 63;
    const int n   = n0 + nl;
    const float bdv = bd[n], biv = bi[n];
    const float spA = softplus_f(A_log[n]);

    for (int bl = 0; bl < 2; ++bl) {
        if (bl) __syncthreads();     // previous batch's Ct reads done
        if ((w >> 1) == bl) {        // waves holding rows of batch bl
            #pragma unroll
            for (int i = 0; i < 4; ++i)
                #pragma unroll
                for (int j = 0; j < 4; ++j)
                    #pragma unroll
                    for (int r = 0; r < 4; ++r)
                        Ct[i * 16 + lq * 4 + r][wn + j * 16 + lr] = acc[i][j][r];
        }
        __syncthreads();

        // local 16-step segment: dec/drv written back in place
        float a = 1.f, hl = 0.f;
        #pragma unroll
        for (int s2 = 0; s2 < 16; ++s2) {
            const int s = seg * 16 + s2;
            const float delta = softplus_f(Ct[s][nl] + bdv);
            const float d  = __expf(-delta * spA);
            const float gv = delta * (Ct[s][64 + nl] + biv);
            Ct[s][nl] = d; Ct[s][64 + nl] = gv;
            a *= d; hl = d * hl + gv;
        }
        grp[seg][nl] = make_float2(a, hl);
        __syncthreads();

        float h = 0.f;
        for (int j = 0; j < seg; ++j) {   // wave-uniform trip count
            const float2 sv = grp[j][nl];
            h = sv.x * h + sv.y;
        }

        const int b = 2 * rb + bl;
        u16* hout = hsb + ((size_t)b * SHOTS + seg * 16) * SDIM + n;
        #pragma unroll
        for (int s2 = 0; s2 < 16; ++s2) {
            const int s = seg * 16 + s2;
            h = Ct[s][nl] * h + Ct[s][64 + nl];
            hout[(size_t)s2 * SDIM] = f2bf(h);
        }
        if (seg == 3) stateb[(size_t)b * SDIM + n] = h;
    }
}

// ---------------------------------------------------------------------------
// gemm_hidden: hidden = hs @ Wo^T + bo + cs, with cs = state @ Ws + bs
// computed INLINE after the K-loop (k-quartered matvec, ushort4 loads,
// partials through reused As LDS). Also writes csbuf (for final_kernel).
// BK=64 -> only 4 K-iterations. BF16OUT: bf16 output. POOL: row-sums.
// ---------------------------------------------------------------------------
template<bool BF16OUT, bool POOL>
__global__ __launch_bounds__(256)
void gemm_hidden(const u16* __restrict__ A, const u16* __restrict__ BT,
                 void* __restrict__ Cv, const float* __restrict__ bo,
                 const float* __restrict__ bs, const u16* __restrict__ Wsb,
                 const float* __restrict__ stateb, float* __restrict__ pooled,
                 float* __restrict__ csbuf, int CB)
{
    __shared__ __align__(16) u16 As[BM * BK];   // 16 KiB (reused: psumL)
    __shared__ __align__(16) u16 Bs[BN * BK];   // 16 KiB
    __shared__ float stL[512];                  // 2 KiB
    __shared__ float csL[2][128];               // 1 KiB

    const int tid = threadIdx.x;
    const int id  = blockIdx.x;
    const int xcd = id & 7, slot = id >> 3;
    const int rb = xcd + 8 * (slot / CB);
    const int cb = slot % CB;
    const int row0 = rb * BM, col0 = cb * BN;
    const int K = 256, ldc = DIM;
    const int b0 = row0 >> 6;                   // first of 2 batches (even)

    // state -> LDS early (written by gemm_pq_scan, stream-ordered)
    stL[tid]       = stateb[(size_t)b0 * SDIM + tid];
    stL[tid + 256] = stateb[(size_t)b0 * SDIM + tid + 256];

    const int l  = tid & 63;
    const int w  = tid >> 6;
    const int wm = (w >> 1) * 64, wn = (w & 1) * 64;
    const int lr = l & 15, lq = l >> 4;

    // BK=64 staging (see comment above)
    const int srow = w * 8 + (l >> 3);
    const int scol = (l & 7) * 8;
    const u16* Ag = A  + (size_t)(row0 + srow) * K + scol;
    const u16* Bg = BT + (size_t)(col0 + srow) * K + scol;
    u16* Asd = &As[(w * 64 + l) * 8];
    u16* Bsd = &Bs[(w * 64 + l) * 8];

    f32x4 acc[4][4];
    #pragma unroll
    for (int i = 0; i < 4; ++i)
        #pragma unroll
        for (int j = 0; j < 4; ++j)
            acc[i][j] = (f32x4){0.f, 0.f, 0.f, 0.f};

    for (int k0 = 0; k0 < K; k0 += BK) {
        #pragma unroll
        for (int i = 0; i < 4; ++i) {
            gld16(Ag + (size_t)(i * 32) * K + k0, Asd + i * 2048);
            gld16(Bg + (size_t)(i * 32) * K + k0, Bsd + i * 2048);
        }
        __syncthreads();

        #pragma unroll
        for (int ks = 0; ks < 2; ++ks) {
            bf16x8 af[4], bfr[4];
            #pragma unroll
            for (int i = 0; i < 4; ++i)
                af[i] = *(const bf16x8*)&As[(wm + i * 16 + lr) * BK + ks * 32 + lq * 8];
            #pragma unroll
            for (int j = 0; j < 4; ++j)
                bfr[j] = *(const bf16x8*)&Bs[(wn + j * 16 + lr) * BK + ks * 32 + lq * 8];
            #pragma unroll
            for (int i = 0; i < 4; ++i)
                #pragma unroll
                for (int j = 0; j < 4; ++j)
                    acc[i][j] = __builtin_amdgcn_mfma_f32_16x16x32_bf16(
                        af[i], bfr[j], acc[i][j], 0, 0, 0);
        }
        __syncthreads();
    }

    // inline cs matvec: thread (kq = tid>>6, blc = (tid>>5)&1, cg = tid&31)
    {
        const int kq = tid >> 6, blc = (tid >> 5) & 1, cg = tid & 31;
        const int kb = kq * 64;
        f32x4 part = {0.f, 0.f, 0.f, 0.f};
        #pragma unroll 8
        for (int k = 0; k < 64; ++k) {
            const float sk = stL[blc * 256 + kb + k];
            const ushort4 wv = *(const ushort4*)
                &Wsb[(size_t)(kb + k) * DIM + col0 + cg * 4];
            part[0] += sk * bf2f(wv.x); part[1] += sk * bf2f(wv.y);
            part[2] += sk * bf2f(wv.z); part[3] += sk * bf2f(wv.w);
        }
        f32x4* psumL = (f32x4*)As;   // As is dead after the K-loop barrier
        psumL[tid] = part;
        __syncthreads();
        if (tid < 64) {
            const int bl2 = tid >> 5, cg2 = tid & 31;
            f32x4 s = psumL[bl2 * 32 + cg2];
            #pragma unroll
            for (int kq2 = 1; kq2 < 4; ++kq2)
                s += psumL[kq2 * 64 + bl2 * 32 + cg2];
            const float4 bv = *(const float4*)(bs + col0 + cg2 * 4);
            float4 o;
            o.x = s[0] + bv.x; o.y = s[1] + bv.y;
            o.z = s[2] + bv.z; o.w = s[3] + bv.w;
            *(float4*)&csL[bl2][cg2 * 4] = o;
            *(float4*)(csbuf + (size_t)(b0 + bl2) * DIM + col0 + cg2 * 4) = o;
        }
        __syncthreads();
    }

    // epilogue: C/D layout col=lane&15, row=quad*4+reg
    float psum[4] = {0.f, 0.f, 0.f, 0.f};
    #pragma unroll
    for (int i = 0; i < 4; ++i) {
        const int grow = row0 + wm + i * 16 + lq * 4;
        const int bl = (grow >> 6) & 1;
        #pragma unroll
        for (int j = 0; j < 4; ++j) {
            const int gcol = col0 + wn + j * 16 + lr;
            const float addv = bo[gcol] + csL[bl][gcol - col0];
            #pragma unroll
            for (int r = 0; r < 4; ++r) {
                const float val = acc[i][j][r] + addv;
                if (BF16OUT) ((u16*)Cv)[(size_t)(grow + r) * ldc + gcol] = f2bf(val);
                else         ((float*)Cv)[(size_t)(grow + r) * ldc + gcol] = val;
                if (POOL) psum[j] += val;
            }
        }
    }
    if (POOL) {
        const int batch_w = (row0 + wm) >> 6;
        #pragma unroll
        for (int j = 0; j < 4; ++j) {
            float v = psum[j];
            v += __shfl_xor(v, 16, 64);
            v += __shfl_xor(v, 32, 64);
            if (lq == 0)
                pooled[(size_t)batch_w * DIM + col0 + wn + j * 16 + lr] = v;
        }
    }
}

// ---------------------------------------------------------------------------
// final_kernel: pooled(sum) -> mean, + class_state, LayerNorm. ~2 MB traffic.
// ---------------------------------------------------------------------------
__global__ __launch_bounds__(1024)
void final_kernel(const float* __restrict__ pooled, const float* __restrict__ cs,
                  const float* __restrict__ gamma, const float* __restrict__ beta,
                  float* __restrict__ out)
{
    const int b = blockIdx.x;
    const int d = threadIdx.x;

    const float p = cs[(size_t)b * DIM + d]
                  + pooled[(size_t)b * DIM + d] * (1.f / SHOTS);

    __shared__ float rsum[1024], rsq[1024];
    rsum[d] = p; rsq[d] = p * p;
    __syncthreads();
    for (int off = 512; off > 0; off >>= 1) {
        if (d < off) { rsum[d] += rsum[d + off]; rsq[d] += rsq[d + off]; }
        __syncthreads();
    }
    const float mu  = rsum[0] * (1.f / DIM);
    const float var = rsq[0] * (1.f / DIM) - mu * mu;
    const float inv = rsqrtf(var + 1e-5f);

    out[(size_t)b * DIM + d] = (p - mu) * inv * gamma[d] + beta[d];
}

// ---------------------------------------------------------------------------

extern "C" void kernel_launch(void* const* d_in, const int* in_sizes, int n_in,
                              void* d_out, int out_size, void* d_ws, size_t ws_size,
                              hipStream_t stream)
{
    const float* X0    = (const float*)d_in[0];
    const float* Wd    = (const float*)d_in[1];
    const float* bd    = (const float*)d_in[2];
    const float* Wi    = (const float*)d_in[3];
    const float* bi    = (const float*)d_in[4];
    const float* A_log = (const float*)d_in[5];
    const float* Wo    = (const float*)d_in[6];
    const float* bo    = (const float*)d_in[7];
    const float* Ws    = (const float*)d_in[8];
    const float* bs    = (const float*)d_in[9];
    const float* gamma = (const float*)d_in[10];
    const float* beta  = (const float*)d_in[11];

    float* out_cr     = (float*)d_out;                  // [BATCH, DIM]
    float* out_hidden = out_cr + (size_t)BATCH * DIM;   // [BATCH, SHOTS, DIM] fp32

    // Xbf (bf16 activations) lives in the out_hidden region as scratch; it is
    // dead before the layer-1 hidden GEMM performs the fp32 out_hidden write.
    u16* Xbf = (u16*)out_hidden;

    // ws layout: ~15 MB <= proven 51.6 MB footprint
    char* w = (char*)d_ws;
    float*  csbuf  = (float*)w;  w += (size_t)BATCH * DIM * 4;          //  1.05 MB
    float*  pooled = (float*)w;  w += (size_t)BATCH * DIM * 4;          //  1.05 MB
    float*  stateb = (float*)w;  w += (size_t)BATCH * SDIM * 4;         //  0.26 MB
    u16*    hsb    = (u16*)w;    w += (size_t)M_TOT * SDIM * 2;         //  8.39 MB
    u16*    WcombT = (u16*)w;    w += (size_t)DEPTH * 512 * 1024 * 2;   //  2.10 MB
    u16*    WoT    = (u16*)w;    w += (size_t)DEPTH * 1024 * 256 * 2;   //  1.05 MB
    u16*    Wsb    = (u16*)w;    w += (size_t)DEPTH * SDIM * DIM * 2;   //  1.05 MB

    // all one-time conversions in ONE dispatch
    prep<<<2688, 256, 0, stream>>>(Wd, Wi, Wo, Ws, X0, WcombT, WoT, Wsb, Xbf);

    for (int l = 0; l < DEPTH; ++l) {
        // PQ GEMM + fused scan: Xbf @ [P|Q-permuted Wcomb] -> hsb, stateb
        gemm_pq_scan<<<512, 256, 0, stream>>>(
            Xbf, WcombT + (size_t)l * 512 * 1024,
            bd + l * SDIM, bi + l * SDIM, A_log + l * SDIM,
            hsb, stateb, 4);
        // hidden = hs @ Wo + bo + (state @ Ws + bs)  (cs inline)
        if (l < DEPTH - 1) {
            gemm_hidden<true, false><<<1024, 256, 0, stream>>>(
                hsb, WoT + (size_t)l * 1024 * 256, Xbf, bo + l * DIM,
                bs + l * DIM, Wsb + (size_t)l * SDIM * DIM, stateb,
                nullptr, csbuf, 8);
        } else {
            gemm_hidden<false, true><<<1024, 256, 0, stream>>>(
                hsb, WoT + (size_t)l * 1024 * 256, out_hidden, bo + l * DIM,
                bs + l * DIM, Wsb + (size_t)l * SDIM * DIM, stateb,
                pooled, csbuf, 8);
        }
    }
    final_kernel<<<BATCH, 1024, 0, stream>>>(pooled, csbuf, gamma, beta, out_cr);
}